// Round 1
// baseline (111.687 us; speedup 1.0000x reference)
//
#include <hip/hip_runtime.h>

#define B_      8
#define S_      4096
#define NSTATE  1024
#define NHEAD   16
#define HD      64
#define NROT    32
#define NVEC    (B_ * S_ * NHEAD)   // 524288 head-vectors
#define VPB     16                  // vectors per block-iteration (= one (b,s) row)

// ---------------------------------------------------------------------------
// Setup kernel: M = R @ rotation_matrix, where R = scan of 32 Givens rotations.
// One block, 256 threads. Writes 64x64 f32 M into d_ws.
// ---------------------------------------------------------------------------
__global__ __launch_bounds__(256) void build_M_kernel(
    const float* __restrict__ thetas,
    const float* __restrict__ rot_pairs,     // (32,2) float, truncate->int
    const float* __restrict__ theta_scale,   // (1,)
    const float* __restrict__ rot_matrix,    // (64,64)
    float* __restrict__ Mout)                // (64,64)
{
    __shared__ float R[HD][HD + 1];
    __shared__ float RM[HD][HD];
    const int t = threadIdx.x;

    for (int k = t; k < HD * HD; k += 256) {
        int r = k >> 6, c = k & 63;
        R[r][c]  = (r == c) ? 1.0f : 0.0f;
        RM[r][c] = rot_matrix[k];
    }
    __syncthreads();

    // Givens scan: R <- R @ G_k. Right-multiplication touches columns i and j:
    //   col_i' = col_i*c + col_j*s ;  col_j' = -col_i*s + col_j*c
    // Thread t owns row t; all updates are row-local (one wave, lockstep).
    if (t < HD) {
        const float ts = theta_scale[0];
        #pragma unroll 1
        for (int k = 0; k < NROT; ++k) {
            const int   i  = (int)rot_pairs[2 * k];
            const int   j  = (int)rot_pairs[2 * k + 1];
            const float th = thetas[k] * ts;
            const float sn = sinf(th);
            const float cs = cosf(th);
            const float ri = R[t][i];
            const float rj = R[t][j];
            if (i == j) {
                // reference's .at chain leaves G[i,i] = c when i == j
                R[t][i] = ri * cs;
            } else {
                R[t][i] = fmaf(ri, cs,  rj * sn);
                R[t][j] = fmaf(rj, cs, -ri * sn);
            }
        }
    }
    __syncthreads();

    // M[d][e] = sum_k R[d][k] * RM[k][e]
    const int e  = t & 63;
    const int dg = t >> 6;          // 4 row-groups of 16
    for (int d = dg * 16; d < dg * 16 + 16; ++d) {
        float acc = 0.0f;
        #pragma unroll
        for (int k = 0; k < HD; ++k) acc = fmaf(R[d][k], RM[k][e], acc);
        Mout[d * HD + e] = acc;
    }
}

// ---------------------------------------------------------------------------
// Main kernel: per head-vector v (64 floats):  xr = x[v] @ M, then RoPE:
//   out[e<32]  = xr[2e]*cos(s*f_e)   - xr[2e+1]*sin(s*f_e)
//   out[e>=32] = xr[2e']*sin(s*f_e') + xr[2e'+1]*cos(s*f_e'),  e' = e-32
// Block = 256 threads (4 waves). Each iteration: stage VPB=16 vectors (4 KB)
// into LDS coalesced; wave w computes vectors w*4..w*4+3; lane e holds column
// M[:,e] in 64 VGPRs; x values come from LDS broadcast float4 reads.
// A chunk of 16 vectors is exactly one (b,s) row -> sin/cos uniform per chunk.
// ---------------------------------------------------------------------------
__global__ __launch_bounds__(256) void rope_main_kernel(
    const float* __restrict__ x,
    const float* __restrict__ Mg,
    const float* __restrict__ inv_freq,
    float* __restrict__ out)
{
    __shared__ float xs[VPB * HD];   // 4 KB
    const int t    = threadIdx.x;
    const int lane = t & 63;
    const int w    = t >> 6;

    float Mcol[HD];
    #pragma unroll
    for (int d = 0; d < HD; ++d) Mcol[d] = Mg[d * HD + lane];

    const int   e2     = lane & 31;
    const float invf   = inv_freq[e2];
    const float INV2PI = 0.15915494309189535f;
    const int   nchunks = NVEC / VPB;   // 32768

    for (int chunk = blockIdx.x; chunk < nchunks; chunk += gridDim.x) {
        const size_t cbase = (size_t)chunk * (VPB * HD);
        const float4 ld = *reinterpret_cast<const float4*>(x + cbase + t * 4);
        __syncthreads();                                   // prior readers done
        *reinterpret_cast<float4*>(xs + t * 4) = ld;
        __syncthreads();

        const float* xb = xs + w * (4 * HD);
        float acc0 = 0.f, acc1 = 0.f, acc2 = 0.f, acc3 = 0.f;
        #pragma unroll
        for (int d4 = 0; d4 < 16; ++d4) {
            const float4 a0 = *reinterpret_cast<const float4*>(xb + 0 * HD + d4 * 4);
            const float4 a1 = *reinterpret_cast<const float4*>(xb + 1 * HD + d4 * 4);
            const float4 a2 = *reinterpret_cast<const float4*>(xb + 2 * HD + d4 * 4);
            const float4 a3 = *reinterpret_cast<const float4*>(xb + 3 * HD + d4 * 4);
            const float m0 = Mcol[d4 * 4 + 0];
            const float m1 = Mcol[d4 * 4 + 1];
            const float m2 = Mcol[d4 * 4 + 2];
            const float m3 = Mcol[d4 * 4 + 3];
            acc0 = fmaf(a0.w, m3, fmaf(a0.z, m2, fmaf(a0.y, m1, fmaf(a0.x, m0, acc0))));
            acc1 = fmaf(a1.w, m3, fmaf(a1.z, m2, fmaf(a1.y, m1, fmaf(a1.x, m0, acc1))));
            acc2 = fmaf(a2.w, m3, fmaf(a2.z, m2, fmaf(a2.y, m1, fmaf(a2.x, m0, acc2))));
            acc3 = fmaf(a3.w, m3, fmaf(a3.z, m2, fmaf(a3.y, m1, fmaf(a3.x, m0, acc3))));
        }

        // sin/cos: position s == chunk & 4095, uniform across the chunk
        const int spos = chunk & (S_ - 1);
        float rev = (float)spos * invf * INV2PI;
        rev = rev - floorf(rev);
        const float sn = __builtin_amdgcn_sinf(rev);   // sin(2*pi*rev)
        const float cs = __builtin_amdgcn_cosf(rev);

        const int src0 = 2 * e2;
        const int src1 = 2 * e2 + 1;
        float* op = out + cbase + (size_t)w * (4 * HD) + lane;

        {
            const float a = __shfl(acc0, src0, 64);
            const float b = __shfl(acc0, src1, 64);
            op[0 * HD] = (lane < 32) ? fmaf(a, cs, -b * sn) : fmaf(a, sn, b * cs);
        }
        {
            const float a = __shfl(acc1, src0, 64);
            const float b = __shfl(acc1, src1, 64);
            op[1 * HD] = (lane < 32) ? fmaf(a, cs, -b * sn) : fmaf(a, sn, b * cs);
        }
        {
            const float a = __shfl(acc2, src0, 64);
            const float b = __shfl(acc2, src1, 64);
            op[2 * HD] = (lane < 32) ? fmaf(a, cs, -b * sn) : fmaf(a, sn, b * cs);
        }
        {
            const float a = __shfl(acc3, src0, 64);
            const float b = __shfl(acc3, src1, 64);
            op[3 * HD] = (lane < 32) ? fmaf(a, cs, -b * sn) : fmaf(a, sn, b * cs);
        }
    }
}

// ---------------------------------------------------------------------------
extern "C" void kernel_launch(void* const* d_in, const int* in_sizes, int n_in,
                              void* d_out, int out_size, void* d_ws, size_t ws_size,
                              hipStream_t stream)
{
    const float* x           = (const float*)d_in[0];
    const float* thetas      = (const float*)d_in[1];
    const float* rot_pairs   = (const float*)d_in[2];
    const float* theta_scale = (const float*)d_in[3];
    const float* rot_matrix  = (const float*)d_in[4];
    const float* inv_freq    = (const float*)d_in[5];
    float*       outp        = (float*)d_out;
    float*       M           = (float*)d_ws;          // 64*64*4 = 16 KB scratch

    build_M_kernel<<<1, 256, 0, stream>>>(thetas, rot_pairs, theta_scale,
                                          rot_matrix, M);

    const int grid = 2048;   // grid-stride over 32768 chunks
    rope_main_kernel<<<grid, 256, 0, stream>>>(x, M, inv_freq, outp);
}

// Round 2
// 72.440 us; speedup vs baseline: 1.5418x; 1.5418x over previous
//
#include <hip/hip_runtime.h>

#define B_      8
#define S_      4096
#define NSTATE  1024
#define NHEAD   16
#define HD      64
#define NROT    32
#define NVEC    (B_ * S_ * NHEAD)     // 524288 head-vectors
#define NCHUNK  (NVEC / 16)           // 32768 16-vector chunks (one per (b,s) row)
#define NGROUP  (NCHUNK / 4)          // 8192 block-iterations (4 waves/block)

typedef __bf16 bf16x8 __attribute__((ext_vector_type(8)));
typedef float  f32x4  __attribute__((ext_vector_type(4)));
typedef unsigned short ushort_t;

// ---------------------------------------------------------------------------
// Setup: M = R(Givens scan) @ rotation_matrix, converted to bf16 and laid out
// in MFMA B-fragment order for v_mfma_f32_16x16x32_bf16:
//   fragment (kt,nt): lane l, elem i  <-  M[d][e],
//     d = kt*32 + 8*(l>>4) + i   (K dim),  e = nt*16 + (l&15)  (N dim)
// Stored as 8 fragments x 512 ushorts = 8 KB in d_ws.
// ---------------------------------------------------------------------------
__global__ __launch_bounds__(256) void build_M_kernel(
    const float* __restrict__ thetas,
    const float* __restrict__ rot_pairs,     // (32,2) float, truncate->int
    const float* __restrict__ theta_scale,   // (1,)
    const float* __restrict__ rot_matrix,    // (64,64)
    ushort_t* __restrict__ Mfrag)            // 4096 ushorts (bf16 bits)
{
    __shared__ float R[HD][HD + 1];
    __shared__ float RM[HD][HD];
    __shared__ float Msh[HD][HD];
    const int t = threadIdx.x;

    for (int k = t; k < HD * HD; k += 256) {
        int r = k >> 6, c = k & 63;
        R[r][c]  = (r == c) ? 1.0f : 0.0f;
        RM[r][c] = rot_matrix[k];
    }
    __syncthreads();

    // Givens scan: R <- R @ G_k (column-pair updates; thread t owns row t).
    if (t < HD) {
        const float ts = theta_scale[0];
        #pragma unroll 1
        for (int k = 0; k < NROT; ++k) {
            const int   i  = (int)rot_pairs[2 * k];
            const int   j  = (int)rot_pairs[2 * k + 1];
            const float th = thetas[k] * ts;
            const float sn = sinf(th);
            const float cs = cosf(th);
            const float ri = R[t][i];
            const float rj = R[t][j];
            if (i == j) {
                R[t][i] = ri * cs;   // reference's .at chain leaves G[i,i]=c
            } else {
                R[t][i] = fmaf(ri, cs,  rj * sn);
                R[t][j] = fmaf(rj, cs, -ri * sn);
            }
        }
    }
    __syncthreads();

    // Msh = R @ RM
    {
        const int e  = t & 63;
        const int dg = t >> 6;
        for (int d = dg * 16; d < dg * 16 + 16; ++d) {
            float acc = 0.0f;
            #pragma unroll
            for (int k = 0; k < HD; ++k) acc = fmaf(R[d][k], RM[k][e], acc);
            Msh[d][e] = acc;
        }
    }
    __syncthreads();

    // Emit bf16 B-fragments
    for (int k = t; k < 8 * 512; k += 256) {
        const int f  = k >> 9;          // fragment 0..7
        const int ln = (k >> 3) & 63;   // lane
        const int i  = k & 7;           // element
        const int kt = f >> 2, nt = f & 3;
        const int d  = kt * 32 + ((ln >> 4) * 8) + i;
        const int e  = nt * 16 + (ln & 15);
        union { __bf16 h; ushort_t u; } cvt;
        cvt.h = (__bf16)Msh[d][e];
        Mfrag[k] = cvt.u;
    }
}

// ---------------------------------------------------------------------------
// Main: each wave processes one 16-vector chunk (= one (b,s) row, 4 KB).
// A-fragments load straight from global (lane l: row l&15, k = 8*(l>>4)..+8
// per 32-wide K-tile), cast f32->bf16, 8 MFMAs produce xr[16][64] in 4 accs.
// RoPE epilogue: C layout col=lane&15,row=(lane>>4)*4+reg; adjacent columns
// (2e',2e'+1) live in lanes l,l^1 -> one DPP shfl_xor(1) pairs them.
// Even lane writes out[r][e'] = x1*cos - x2*sin; odd writes out[r][32+e'].
// No LDS anywhere.
// ---------------------------------------------------------------------------
__global__ __launch_bounds__(256) void rope_mfma_kernel(
    const float* __restrict__ x,
    const ushort_t* __restrict__ Mfrag,
    const float* __restrict__ inv_freq,
    float* __restrict__ out)
{
    const int t    = threadIdx.x;
    const int lane = t & 63;
    const int w    = t >> 6;
    const int l15  = lane & 15;
    const int lhi  = lane >> 4;

    // B fragments: 8 x bf16x8 = 32 VGPRs, loaded once
    bf16x8 bf[2][4];
    #pragma unroll
    for (int kt = 0; kt < 2; ++kt)
        #pragma unroll
        for (int nt = 0; nt < 4; ++nt)
            bf[kt][nt] = *reinterpret_cast<const bf16x8*>(
                Mfrag + ((kt * 4 + nt) * 512 + lane * 8));

    const int  ep    = l15 >> 1;                 // e' within 8-wide group
    const bool even  = (lane & 1) == 0;
    const float INV2PI = 0.15915494309189535f;
    float invf[4];
    #pragma unroll
    for (int nt = 0; nt < 4; ++nt) invf[nt] = inv_freq[nt * 8 + ep];

    const int aoff = l15 * 64 + lhi * 8;         // float offset within 4 KB chunk

    for (int g = blockIdx.x; g < NGROUP; g += gridDim.x) {
        const int    chunk = g * 4 + w;          // 0..32767
        const size_t base  = (size_t)chunk * 1024;
        const float* xp    = x + base + aoff;

        const float4 q0 = *reinterpret_cast<const float4*>(xp);
        const float4 q1 = *reinterpret_cast<const float4*>(xp + 4);
        const float4 q2 = *reinterpret_cast<const float4*>(xp + 32);
        const float4 q3 = *reinterpret_cast<const float4*>(xp + 36);

        bf16x8 a0, a1;
        a0[0] = (__bf16)q0.x; a0[1] = (__bf16)q0.y; a0[2] = (__bf16)q0.z; a0[3] = (__bf16)q0.w;
        a0[4] = (__bf16)q1.x; a0[5] = (__bf16)q1.y; a0[6] = (__bf16)q1.z; a0[7] = (__bf16)q1.w;
        a1[0] = (__bf16)q2.x; a1[1] = (__bf16)q2.y; a1[2] = (__bf16)q2.z; a1[3] = (__bf16)q2.w;
        a1[4] = (__bf16)q3.x; a1[5] = (__bf16)q3.y; a1[6] = (__bf16)q3.z; a1[7] = (__bf16)q3.w;

        f32x4 acc[4];
        #pragma unroll
        for (int nt = 0; nt < 4; ++nt) {
            acc[nt] = (f32x4){0.f, 0.f, 0.f, 0.f};
            acc[nt] = __builtin_amdgcn_mfma_f32_16x16x32_bf16(a0, bf[0][nt], acc[nt], 0, 0, 0);
            acc[nt] = __builtin_amdgcn_mfma_f32_16x16x32_bf16(a1, bf[1][nt], acc[nt], 0, 0, 0);
        }

        // per-chunk trig (position s uniform across the wave's chunk)
        const int s = chunk & (S_ - 1);
        float sn[4], cs[4];
        #pragma unroll
        for (int nt = 0; nt < 4; ++nt) {
            float rev = (float)s * invf[nt] * INV2PI;
            rev -= floorf(rev);
            sn[nt] = __builtin_amdgcn_sinf(rev);
            cs[nt] = __builtin_amdgcn_cosf(rev);
        }

        float* op = out + base;
        #pragma unroll
        for (int nt = 0; nt < 4; ++nt) {
            const int colout = even ? (nt * 8 + ep) : (32 + nt * 8 + ep);
            #pragma unroll
            for (int j = 0; j < 4; ++j) {
                const float own = acc[nt][j];
                const float oth = __shfl_xor(own, 1, 64);
                const float x1  = even ? own : oth;
                const float x2  = even ? oth : own;
                const float res = even ? fmaf(x1, cs[nt], -x2 * sn[nt])
                                       : fmaf(x2, cs[nt],  x1 * sn[nt]);
                const int r = lhi * 4 + j;
                op[r * 64 + colout] = res;
            }
        }
    }
}

// ---------------------------------------------------------------------------
extern "C" void kernel_launch(void* const* d_in, const int* in_sizes, int n_in,
                              void* d_out, int out_size, void* d_ws, size_t ws_size,
                              hipStream_t stream)
{
    const float* x           = (const float*)d_in[0];
    const float* thetas      = (const float*)d_in[1];
    const float* rot_pairs   = (const float*)d_in[2];
    const float* theta_scale = (const float*)d_in[3];
    const float* rot_matrix  = (const float*)d_in[4];
    const float* inv_freq    = (const float*)d_in[5];
    float*       outp        = (float*)d_out;
    ushort_t*    Mfrag       = (ushort_t*)d_ws;       // 8 KB

    build_M_kernel<<<1, 256, 0, stream>>>(thetas, rot_pairs, theta_scale,
                                          rot_matrix, Mfrag);

    rope_mfma_kernel<<<2048, 256, 0, stream>>>(x, Mfrag, inv_freq, outp);
}

// Round 3
// 67.916 us; speedup vs baseline: 1.6445x; 1.0666x over previous
//
#include <hip/hip_runtime.h>

#define S_      4096
#define HD      64
#define NROT    32
#define NCHUNK  32768                 // 16-vector chunks (one per (b,s) row)
#define NBLK    2048
#define WPB     4                     // waves per block
#define NWAVE   (NBLK * WPB)          // 8192
#define NITER   (NCHUNK / NWAVE)      // 4 chunks per wave

typedef __bf16 bf16x8 __attribute__((ext_vector_type(8)));
typedef float  f32x4  __attribute__((ext_vector_type(4)));
typedef unsigned short ushort_t;

// ---------------------------------------------------------------------------
// Setup: M = R(Givens scan) @ rotation_matrix, bf16, MFMA-B-fragment order
// with a baked column permutation pi so the epilogue's stores coalesce:
//   fragment (kt,nt): lane l, elem i  <-  M[d][e]
//     d = kt*32 + 8*(l>>4) + i                  (K dim)
//     n = l&15;  e = 8*(n>>1) + 2*nt + (n&1)    (permuted N dim)
// ---------------------------------------------------------------------------
__global__ __launch_bounds__(256) void build_M_kernel(
    const float* __restrict__ thetas,
    const float* __restrict__ rot_pairs,
    const float* __restrict__ theta_scale,
    const float* __restrict__ rot_matrix,
    ushort_t* __restrict__ Mfrag)            // 4096 ushorts (8 KB)
{
    __shared__ float R[HD][HD + 1];
    __shared__ float RM[HD][HD];
    __shared__ float Msh[HD][HD];
    const int t = threadIdx.x;

    for (int k = t; k < HD * HD; k += 256) {
        int r = k >> 6, c = k & 63;
        R[r][c]  = (r == c) ? 1.0f : 0.0f;
        RM[r][c] = rot_matrix[k];
    }
    __syncthreads();

    if (t < HD) {
        const float ts = theta_scale[0];
        #pragma unroll 1
        for (int k = 0; k < NROT; ++k) {
            const int   i  = (int)rot_pairs[2 * k];
            const int   j  = (int)rot_pairs[2 * k + 1];
            const float th = thetas[k] * ts;
            const float sn = sinf(th);
            const float cs = cosf(th);
            const float ri = R[t][i];
            const float rj = R[t][j];
            if (i == j) {
                R[t][i] = ri * cs;   // reference's .at chain leaves G[i,i]=c
            } else {
                R[t][i] = fmaf(ri, cs,  rj * sn);
                R[t][j] = fmaf(rj, cs, -ri * sn);
            }
        }
    }
    __syncthreads();

    {
        const int e  = t & 63;
        const int dg = t >> 6;
        for (int d = dg * 16; d < dg * 16 + 16; ++d) {
            float acc = 0.0f;
            #pragma unroll
            for (int k = 0; k < HD; ++k) acc = fmaf(R[d][k], RM[k][e], acc);
            Msh[d][e] = acc;
        }
    }
    __syncthreads();

    for (int k = t; k < 8 * 512; k += 256) {
        const int f  = k >> 9;          // fragment 0..7
        const int ln = (k >> 3) & 63;   // lane
        const int i  = k & 7;           // element
        const int kt = f >> 2, nt = f & 3;
        const int d  = kt * 32 + ((ln >> 4) * 8) + i;
        const int n  = ln & 15;
        const int e  = 8 * (n >> 1) + 2 * nt + (n & 1);   // pi permutation
        union { __bf16 h; ushort_t u; } cvt;
        cvt.h = (__bf16)Msh[d][e];
        Mfrag[k] = cvt.u;
    }
}

// ---------------------------------------------------------------------------
__device__ __forceinline__ void gld16(const float* g, float* l)
{
    __builtin_amdgcn_global_load_lds(
        (const __attribute__((address_space(1))) void*)g,
        (__attribute__((address_space(3))) void*)l, 16, 0, 0);
}

// ---------------------------------------------------------------------------
// Main: one wave per 16-vector chunk iteration. Coalesced global_load_lds
// stages the 4 KB chunk to a per-wave LDS buffer (no barriers ever). A-frags
// ds_read from LDS, 8 MFMAs, RoPE epilogue via one shfl_xor(1); the baked pi
// makes each lane's 4 results contiguous -> 4 coalesced dwordx4 stores.
// Next chunk's loads issue right after the A-reads retire (buffer dead),
// hiding HBM latency under compute+stores; vmcnt(4) at loop head.
// ---------------------------------------------------------------------------
__global__ __launch_bounds__(256) void rope_mfma_kernel(
    const float* __restrict__ x,
    const ushort_t* __restrict__ Mfrag,
    const float* __restrict__ inv_freq,
    float* __restrict__ out)
{
    __shared__ __align__(16) float lbuf[WPB * 1024];   // 16 KB: 4 KB per wave
    const int t    = threadIdx.x;
    const int lane = t & 63;
    const int w    = t >> 6;
    const int l15  = lane & 15;
    const int lhi  = lane >> 4;
    const int u    = l15 >> 1;
    const bool even = (lane & 1) == 0;
    float* wbuf = lbuf + w * 1024;

    // B fragments (32 VGPRs)
    bf16x8 bf[2][4];
    #pragma unroll
    for (int kt = 0; kt < 2; ++kt)
        #pragma unroll
        for (int nt = 0; nt < 4; ++nt)
            bf[kt][nt] = *reinterpret_cast<const bf16x8*>(
                Mfrag + ((kt * 4 + nt) * 512 + lane * 8));

    // 4 contiguous freqs per lane: out cols 4u..4u+3 (mod 32)
    const f32x4 invf = *reinterpret_cast<const f32x4*>(inv_freq + 4 * u);
    const float INV2PI = 0.15915494309189535f;

    int c = blockIdx.x * WPB + w;                 // first chunk for this wave
    const float* xw = x + (size_t)c * 1024;

    // prologue: stage chunk 0
    #pragma unroll
    for (int k = 0; k < 4; ++k)
        gld16(xw + k * 256 + lane * 4, wbuf + k * 256);
    asm volatile("s_waitcnt vmcnt(0)" ::: "memory");

    #pragma unroll 1
    for (int it = 0; it < NITER; ++it) {
        if (it) asm volatile("s_waitcnt vmcnt(4)" ::: "memory");
        __builtin_amdgcn_sched_barrier(0);

        // A fragments from LDS (row l15, k-cols lhi*8..+7 per k-tile)
        const float* ap = wbuf + l15 * 64 + lhi * 8;
        const f32x4 q0 = *reinterpret_cast<const f32x4*>(ap);
        const f32x4 q1 = *reinterpret_cast<const f32x4*>(ap + 4);
        const f32x4 q2 = *reinterpret_cast<const f32x4*>(ap + 32);
        const f32x4 q3 = *reinterpret_cast<const f32x4*>(ap + 36);
        asm volatile("s_waitcnt lgkmcnt(0)" ::: "memory");
        __builtin_amdgcn_sched_barrier(0);

        // prefetch next chunk into the (now dead) buffer
        if (it + 1 < NITER) {
            const float* xn = x + (size_t)(c + NWAVE) * 1024;
            #pragma unroll
            for (int k = 0; k < 4; ++k)
                gld16(xn + k * 256 + lane * 4, wbuf + k * 256);
        }

        bf16x8 a0, a1;
        #pragma unroll
        for (int i = 0; i < 4; ++i) {
            a0[i]     = (__bf16)q0[i];
            a0[4 + i] = (__bf16)q1[i];
            a1[i]     = (__bf16)q2[i];
            a1[4 + i] = (__bf16)q3[i];
        }

        f32x4 acc[4];
        #pragma unroll
        for (int nt = 0; nt < 4; ++nt) {
            acc[nt] = (f32x4){0.f, 0.f, 0.f, 0.f};
            acc[nt] = __builtin_amdgcn_mfma_f32_16x16x32_bf16(a0, bf[0][nt], acc[nt], 0, 0, 0);
            acc[nt] = __builtin_amdgcn_mfma_f32_16x16x32_bf16(a1, bf[1][nt], acc[nt], 0, 0, 0);
        }

        // trig: position s uniform over the chunk; freqs per lane from invf
        const int s = c & (S_ - 1);
        float cs[4], sn2[4];
        #pragma unroll
        for (int nt = 0; nt < 4; ++nt) {
            float rev = (float)s * invf[nt] * INV2PI;
            rev -= floorf(rev);
            const float sv = __builtin_amdgcn_sinf(rev);
            cs[nt]  = __builtin_amdgcn_cosf(rev);
            sn2[nt] = even ? -sv : sv;
        }

        // epilogue: res = own*cos +/- partner*sin ; pi makes nt-results the
        // 4 consecutive floats at out col (even?0:32)+4u
        float* outc = out + (size_t)c * 1024;
        #pragma unroll
        for (int j = 0; j < 4; ++j) {
            f32x4 res;
            #pragma unroll
            for (int nt = 0; nt < 4; ++nt) {
                const float own = acc[nt][j];
                const float oth = __shfl_xor(own, 1, 64);
                res[nt] = fmaf(oth, sn2[nt], own * cs[nt]);
            }
            const int row  = lhi * 4 + j;
            const int col0 = (even ? 0 : 32) + 4 * u;
            *reinterpret_cast<f32x4*>(outc + row * 64 + col0) = res;
        }

        c += NWAVE;
    }
}

// ---------------------------------------------------------------------------
extern "C" void kernel_launch(void* const* d_in, const int* in_sizes, int n_in,
                              void* d_out, int out_size, void* d_ws, size_t ws_size,
                              hipStream_t stream)
{
    const float* x           = (const float*)d_in[0];
    const float* thetas      = (const float*)d_in[1];
    const float* rot_pairs   = (const float*)d_in[2];
    const float* theta_scale = (const float*)d_in[3];
    const float* rot_matrix  = (const float*)d_in[4];
    const float* inv_freq    = (const float*)d_in[5];
    float*       outp        = (float*)d_out;
    ushort_t*    Mfrag       = (ushort_t*)d_ws;       // 8 KB

    build_M_kernel<<<1, 256, 0, stream>>>(thetas, rot_pairs, theta_scale,
                                          rot_matrix, Mfrag);

    rope_mfma_kernel<<<NBLK, 256, 0, stream>>>(x, Mfrag, inv_freq, outp);
}